// Round 1
// baseline (7377.624 us; speedup 1.0000x reference)
//
#include <hip/hip_runtime.h>

typedef unsigned short u16;
typedef __attribute__((ext_vector_type(4))) float f32x4;
typedef __attribute__((ext_vector_type(8))) short s16x8;

// ---------- small helpers ----------
__device__ __forceinline__ u16 f2bf(float f) {
  union { float f; unsigned u; } x; x.f = f;
  unsigned r = x.u + 0x7FFFu + ((x.u >> 16) & 1u);   // RNE
  return (u16)(r >> 16);
}
__device__ __forceinline__ float bf2f(u16 h) {
  union { unsigned u; float f; } x; x.u = ((unsigned)h) << 16;
  return x.f;
}
__device__ __forceinline__ void gload16(const void* g, void* l) {
  __builtin_amdgcn_global_load_lds((__attribute__((address_space(1))) void*)g,
                                   (__attribute__((address_space(3))) void*)l,
                                   16, 0, 0);
}
__device__ __forceinline__ float leaky(float v) { return v >= 0.f ? v : 0.01f * v; }

// ---------- elementwise / prep kernels ----------
__global__ void k_fill(float* __restrict__ p, int n, float v) {
  int i = blockIdx.x * 256 + threadIdx.x;
  if (i < n) p[i] = v;
}
__global__ void k_deg(const int* __restrict__ dst, const float* __restrict__ w,
                      float* __restrict__ deg, int E) {
  int e = blockIdx.x * 256 + threadIdx.x;
  if (e < E) unsafeAtomicAdd(&deg[dst[e]], w[e]);
}
__global__ void k_rsqrt(float* __restrict__ p, int n) {
  int i = blockIdx.x * 256 + threadIdx.x;
  if (i < n) p[i] = rsqrtf(p[i]);   // deg >= 2.0 always (self-loop weight)
}
__global__ void k_flagset(int* __restrict__ flag, const int* __restrict__ idx, int n) {
  int i = blockIdx.x * 256 + threadIdx.x;
  if (i < n) flag[idx[i]] = 1;
}
// x [M,K] f32 -> xb [M,Kpad] bf16 (zero pad K..Kpad). grid: (ceil(Kpad/256), M)
__global__ void k_convert(const float* __restrict__ x, u16* __restrict__ xb,
                          int K, int Kpad) {
  int k = blockIdx.x * 256 + threadIdx.x;
  int m = blockIdx.y;
  if (k >= Kpad) return;
  xb[(size_t)m * Kpad + k] = (k < K) ? f2bf(x[(size_t)m * K + k]) : (u16)0;
}
// W [K,N] f32 -> Wt [Npad,Kpad] bf16 transposed, zero-padded. grid: (Kpad/32, Npad/32)
__global__ void k_wt(const float* __restrict__ W, u16* __restrict__ Wt,
                     int K, int N, int Kpad) {
  __shared__ float t[32][33];
  int tx = threadIdx.x & 31, ty = threadIdx.x >> 5;   // 256 thr: ty 0..7
  int k0 = blockIdx.x * 32, n0 = blockIdx.y * 32;
  #pragma unroll
  for (int r = 0; r < 4; ++r) {
    int k = k0 + ty + r * 8;
    t[ty + r * 8][tx] = (k < K && (n0 + tx) < N) ? W[(size_t)k * N + n0 + tx] : 0.f;
  }
  __syncthreads();
  #pragma unroll
  for (int r = 0; r < 4; ++r) {
    int n = n0 + ty + r * 8;
    Wt[(size_t)n * Kpad + k0 + tx] = f2bf(t[tx][ty + r * 8]);
  }
}
// p_embeddings -> enc_in cols [300,1344). grid: (5, 8192)
__global__ void k_pemb(const float* __restrict__ pe, u16* __restrict__ enc_in) {
  int j = blockIdx.x * 256 + threadIdx.x;
  int b = blockIdx.y;
  if (j >= 1044) return;
  enc_in[(size_t)b * 1344 + 300 + j] =
      (j < 1024) ? f2bf(pe[(size_t)b * 1024 + j]) : (u16)0;
}

// ---------- GCN scatter: agg[dst] += h[src] * norm (flag-gated) ----------
__global__ void k_scatter(const u16* __restrict__ h, float* __restrict__ agg,
                          const int* __restrict__ se, const int* __restrict__ de,
                          const float* __restrict__ w, const float* __restrict__ dinv,
                          const int* __restrict__ flag, int F) {
  int e = blockIdx.x;
  int d = de[e];
  if (flag[d] == 0) return;
  int s = se[e];
  float nrm = dinv[s] * w[e] * dinv[d];
  const u16* hr = h + (size_t)s * F;
  float* ar = agg + (size_t)d * F;
  for (int f0 = threadIdx.x * 4; f0 < F; f0 += blockDim.x * 4) {
    ushort4 hv = *(const ushort4*)(hr + f0);
    unsafeAtomicAdd(ar + f0 + 0, bf2f(hv.x) * nrm);
    unsafeAtomicAdd(ar + f0 + 1, bf2f(hv.y) * nrm);
    unsafeAtomicAdd(ar + f0 + 2, bf2f(hv.z) * nrm);
    unsafeAtomicAdd(ar + f0 + 3, bf2f(hv.w) * nrm);
  }
}

// ---------- GCN gather: out[b] = leaky(agg[row] + h[row]*2*dinv^2 + bias) ----------
__global__ void k_gather(const float* __restrict__ agg, const u16* __restrict__ h,
                         const float* __restrict__ dinv, const int* __restrict__ idx,
                         const float* __restrict__ bias, u16* __restrict__ outb,
                         int Freal, int Fpad, int ldo) {
  int b = blockIdx.x;
  int row = idx[b];
  float sn = 2.0f * dinv[row] * dinv[row];
  const float* ar = agg + (size_t)row * Fpad;
  const u16* hr = h + (size_t)row * Fpad;
  u16* orow = outb + (size_t)b * ldo;
  for (int f = threadIdx.x; f < Freal; f += blockDim.x) {
    float v = ar[f] + bf2f(hr[f]) * sn + bias[f];
    orow[f] = f2bf(leaky(v));
  }
}

// ---------- bf16 MFMA GEMM: C[M,N] = A[M,K] @ Bt[N,K]^T ----------
// 128x128 tile, BK=32, 4 waves (2x2), 64x64 per wave, 16x16x32 MFMA.
// EPI 0: store bf16 (h matrices).  EPI 1: +bias, BN, leaky -> f32 + bf16 (encoder).
// EPI 2: +bias, leaky, BN -> f32 (fc1).
template<int EPI>
__global__ __launch_bounds__(256) void gemm_k(
    const u16* __restrict__ A, const u16* __restrict__ Bt, int K,
    u16* __restrict__ Cb, int ldcb, float* __restrict__ Cf, int ldcf,
    const float* __restrict__ bias, const float* __restrict__ gamma,
    const float* __restrict__ beta, const float* __restrict__ mean,
    const float* __restrict__ var)
{
  __shared__ u16 As[2][128 * 32];
  __shared__ u16 Bs[2][128 * 32];
  const int tid = threadIdx.x;
  const int lane = tid & 63, wid = tid >> 6;
  const int wr = wid >> 1, wc = wid & 1;
  const int llo = lane & 15, lhi = lane >> 4;
  const int m0 = blockIdx.y * 128, n0 = blockIdx.x * 128;

  f32x4 acc[4][4] = {};
  const int NT = K >> 5;

  auto stage = [&](int b, int t) {
    const int k0 = t << 5;
    #pragma unroll
    for (int r = 0; r < 2; ++r) {
      const int i  = (r << 8) + (wid << 6) + lane;   // 0..511 segment id
      const int ib = (r << 8) + (wid << 6);          // wave-uniform base
      gload16(A  + (size_t)(m0 + (i >> 2)) * K + (k0 + (i & 3) * 8), &As[b][ib * 8]);
      gload16(Bt + (size_t)(n0 + (i >> 2)) * K + (k0 + (i & 3) * 8), &Bs[b][ib * 8]);
    }
  };

  stage(0, 0);
  int cur = 0;
  for (int t = 0; t < NT; ++t) {
    __syncthreads();                       // buf[cur] staged (vmcnt drained)
    if (t + 1 < NT) stage(cur ^ 1, t + 1); // prefetch next tile
    s16x8 af[4], bfr[4];
    #pragma unroll
    for (int m = 0; m < 4; ++m)
      af[m] = *(const s16x8*)&As[cur][(wr * 64 + m * 16 + llo) * 32 + lhi * 8];
    #pragma unroll
    for (int n = 0; n < 4; ++n)
      bfr[n] = *(const s16x8*)&Bs[cur][(wc * 64 + n * 16 + llo) * 32 + lhi * 8];
    #pragma unroll
    for (int m = 0; m < 4; ++m)
      #pragma unroll
      for (int n = 0; n < 4; ++n)
        acc[m][n] = __builtin_amdgcn_mfma_f32_16x16x32_bf16(af[m], bfr[n], acc[m][n], 0, 0, 0);
    __syncthreads();
    cur ^= 1;
  }

  const int crow = m0 + wr * 64, ccol = n0 + wc * 64;
  #pragma unroll
  for (int n = 0; n < 4; ++n) {
    const int col = ccol + n * 16 + llo;
    float bi = 0.f, g = 0.f, be = 0.f, mu = 0.f, iv = 0.f;
    if constexpr (EPI >= 1) {
      bi = bias[col]; g = gamma[col]; be = beta[col]; mu = mean[col];
      iv = rsqrtf(var[col] + 1e-5f);
    }
    #pragma unroll
    for (int m = 0; m < 4; ++m) {
      #pragma unroll
      for (int j = 0; j < 4; ++j) {
        const int row = crow + m * 16 + lhi * 4 + j;
        float v = acc[m][n][j];
        if constexpr (EPI == 0) {
          Cb[(size_t)row * ldcb + col] = f2bf(v);
        } else if constexpr (EPI == 1) {
          v += bi;
          v = g * (v - mu) * iv + be;     // BN then leaky (encoder)
          v = leaky(v);
          Cf[(size_t)row * ldcf + col] = v;
          Cb[(size_t)row * ldcb + col] = f2bf(v);
        } else {
          v += bi;
          v = leaky(v);                   // leaky then BN (fc)
          v = g * (v - mu) * iv + be;
          Cf[(size_t)row * ldcf + col] = v;
        }
      }
    }
  }
}

// ---------- fc2: y[r] = relu(dot(h[r,:512], w) + b), wave per row ----------
__global__ void k_fc2(const float* __restrict__ h, const float* __restrict__ w,
                      const float* __restrict__ b, float* __restrict__ y) {
  int r = blockIdx.x * 4 + (threadIdx.x >> 6);
  int lane = threadIdx.x & 63;
  const float* hr = h + (size_t)r * 512;
  float s = 0.f;
  #pragma unroll
  for (int j = 0; j < 8; ++j) s += hr[lane + j * 64] * w[lane + j * 64];
  #pragma unroll
  for (int off = 32; off > 0; off >>= 1) s += __shfl_down(s, off);
  if (lane == 0) y[r] = fmaxf(s + b[0], 0.f);
}

// ---------- host ----------
extern "C" void kernel_launch(void* const* d_in, const int* in_sizes, int n_in,
                              void* d_out, int out_size, void* d_ws, size_t ws_size,
                              hipStream_t stream) {
  constexpr int NB  = 8192;
  constexpr int ND  = 10000, NP = 20000;
  constexpr int ED  = 320000, EP = 640000;
  constexpr int K1  = 300, K1P = 320, N1 = 300, N1P = 384;
  constexpr int MD_P = 10112;               // 79*128
  constexpr int K2  = 1024, N2 = 1024;
  constexpr int K3  = 2812, K3P = 2816, N3 = 1024;
  constexpr int MP_P = 20096;               // 4*4096 + 29*128
  constexpr int CH  = 4096;
  constexpr int KE  = 1324, KEP = 1344, NE = 512;
  constexpr int KF  = 2560, NF = 512;

  const int*   d_index = (const int*)d_in[0];
  const int*   p_index = (const int*)d_in[1];
  const float* p_emb   = (const float*)d_in[2];
  const float* d_vecs  = (const float*)d_in[3];
  const float* d_ecfps = (const float*)d_in[4];
  const float* p_gos   = (const float*)d_in[5];
  const int*   d_ei    = (const int*)d_in[6];
  const float* d_ew    = (const float*)d_in[7];
  const int*   p_ei    = (const int*)d_in[8];
  const float* p_ew    = (const float*)d_in[9];
  const float* W_dvec  = (const float*)d_in[10];
  const float* b_dvec  = (const float*)d_in[11];
  const float* W_decfp = (const float*)d_in[12];
  const float* b_decfp = (const float*)d_in[13];
  const float* W_pgo   = (const float*)d_in[14];
  const float* b_pgo   = (const float*)d_in[15];
  const float* enc_W   = (const float*)d_in[16];
  const float* enc_b   = (const float*)d_in[17];
  const float* enc_g   = (const float*)d_in[18];
  const float* enc_be  = (const float*)d_in[19];
  const float* enc_mu  = (const float*)d_in[20];
  const float* enc_va  = (const float*)d_in[21];
  const float* fc1_W   = (const float*)d_in[22];
  const float* fc1_b   = (const float*)d_in[23];
  const float* fc_g    = (const float*)d_in[24];
  const float* fc_be   = (const float*)d_in[25];
  const float* fc_mu   = (const float*)d_in[26];
  const float* fc_va   = (const float*)d_in[27];
  const float* fc2_W   = (const float*)d_in[28];
  const float* fc2_b   = (const float*)d_in[29];

  char* ws = (char*)d_ws;
  size_t off = 0;
  auto alloc = [&](size_t bytes) -> char* {
    char* p = ws + off;
    off += (bytes + 255) & ~(size_t)255;
    return p;
  };
  float* deg_d  = (float*)alloc((size_t)ND * 4);
  float* deg_p  = (float*)alloc((size_t)NP * 4);
  int*   flag_d = (int*)  alloc((size_t)ND * 4);
  int*   flag_p = (int*)  alloc((size_t)NP * 4);
  u16*   xb1    = (u16*)  alloc((size_t)MD_P * K1P * 2);
  u16*   xb2    = (u16*)  alloc((size_t)MD_P * K2 * 2);
  u16*   xch    = (u16*)  alloc((size_t)CH * K3P * 2);
  u16*   W1t    = (u16*)  alloc((size_t)N1P * K1P * 2);
  u16*   W2t    = (u16*)  alloc((size_t)N2 * K2 * 2);
  u16*   W3t    = (u16*)  alloc((size_t)N3 * K3P * 2);
  u16*   encWt  = (u16*)  alloc((size_t)NE * KEP * 2);
  u16*   fc1Wt  = (u16*)  alloc((size_t)NF * KF * 2);
  u16*   h1     = (u16*)  alloc((size_t)MD_P * N1P * 2);
  u16*   h2     = (u16*)  alloc((size_t)MD_P * N2 * 2);
  u16*   h3     = (u16*)  alloc((size_t)MP_P * N3 * 2);
  float* agg    = (float*)alloc((size_t)MP_P * N3 * 4);   // reused as h_fc1 later
  u16*   enc_in = (u16*)  alloc((size_t)NB * KEP * 2);
  u16*   fc1_in = (u16*)  alloc((size_t)NB * KF * 2);
  float* h_fc1  = agg;                                    // alias (agg dead by fc1)
  if (off > ws_size) return;                              // ws too small: bail loudly

  float* y_out    = (float*)d_out;
  float* feat_out = (float*)d_out + NB;

  // ---- degrees, flags ----
  k_fill<<<dim3((ND + 255) / 256), 256, 0, stream>>>(deg_d, ND, 2.0f);
  k_fill<<<dim3((NP + 255) / 256), 256, 0, stream>>>(deg_p, NP, 2.0f);
  k_deg<<<dim3((ED + 255) / 256), 256, 0, stream>>>(d_ei + ED, d_ew, deg_d, ED);
  k_deg<<<dim3((EP + 255) / 256), 256, 0, stream>>>(p_ei + EP, p_ew, deg_p, EP);
  k_rsqrt<<<dim3((ND + 255) / 256), 256, 0, stream>>>(deg_d, ND);
  k_rsqrt<<<dim3((NP + 255) / 256), 256, 0, stream>>>(deg_p, NP);
  hipMemsetAsync(flag_d, 0, (size_t)ND * 4, stream);
  hipMemsetAsync(flag_p, 0, (size_t)NP * 4, stream);
  k_flagset<<<dim3(32), 256, 0, stream>>>(flag_d, d_index, NB);
  k_flagset<<<dim3(32), 256, 0, stream>>>(flag_p, p_index, NB);

  // ---- weight transpose-converts (f32 [K,N] -> bf16 [Npad,Kpad]) ----
  k_wt<<<dim3(K1P / 32, N1P / 32), 256, 0, stream>>>(W_dvec, W1t, K1, N1, K1P);
  k_wt<<<dim3(K2 / 32, N2 / 32), 256, 0, stream>>>(W_decfp, W2t, K2, N2, K2);
  k_wt<<<dim3(K3P / 32, N3 / 32), 256, 0, stream>>>(W_pgo, W3t, K3, N3, K3P);
  k_wt<<<dim3(KEP / 32, NE / 32), 256, 0, stream>>>(enc_W, encWt, KE, NE, KEP);
  k_wt<<<dim3(KF / 32, NF / 32), 256, 0, stream>>>(fc1_W, fc1Wt, KF, NF, KF);

  // ---- feature converts ----
  k_convert<<<dim3((K1P + 255) / 256, ND), 256, 0, stream>>>(d_vecs, xb1, K1, K1P);
  k_convert<<<dim3(K2 / 256, ND), 256, 0, stream>>>(d_ecfps, xb2, K2, K2);
  k_pemb<<<dim3(5, NB), 256, 0, stream>>>(p_emb, enc_in);

  // ---- GCN1 (d_vecs, 300->300) ----
  gemm_k<0><<<dim3(N1P / 128, MD_P / 128), 256, 0, stream>>>(
      xb1, W1t, K1P, h1, N1P, nullptr, 0, nullptr, nullptr, nullptr, nullptr, nullptr);
  hipMemsetAsync(agg, 0, (size_t)MD_P * N1P * 4, stream);
  k_scatter<<<dim3(ED), 256, 0, stream>>>(h1, agg, d_ei, d_ei + ED, d_ew, deg_d, flag_d, N1P);
  k_gather<<<dim3(NB), 256, 0, stream>>>(agg, h1, deg_d, d_index, b_dvec, enc_in, N1, N1P, KEP);

  // ---- GCN2 (d_ecfps, 1024->1024) ----
  gemm_k<0><<<dim3(N2 / 128, MD_P / 128), 256, 0, stream>>>(
      xb2, W2t, K2, h2, N2, nullptr, 0, nullptr, nullptr, nullptr, nullptr, nullptr);
  hipMemsetAsync(agg, 0, (size_t)MD_P * N2 * 4, stream);
  k_scatter<<<dim3(ED), 256, 0, stream>>>(h2, agg, d_ei, d_ei + ED, d_ew, deg_d, flag_d, N2);
  k_gather<<<dim3(NB), 256, 0, stream>>>(agg, h2, deg_d, d_index, b_decfp, fc1_in + 512, N2, N2, KF);

  // ---- GCN3 (p_gos, 2812->1024), chunked conversion to bound ws ----
  for (int c = 0; c < 5; ++c) {
    int r0 = c * CH;
    int rows = (NP - r0 < CH) ? (NP - r0) : CH;
    k_convert<<<dim3((K3P + 255) / 256, rows), 256, 0, stream>>>(
        p_gos + (size_t)r0 * K3, xch, K3, K3P);
    gemm_k<0><<<dim3(N3 / 128, (rows + 127) / 128), 256, 0, stream>>>(
        xch, W3t, K3P, h3 + (size_t)r0 * N3, N3, nullptr, 0,
        nullptr, nullptr, nullptr, nullptr, nullptr);
  }
  hipMemsetAsync(agg, 0, (size_t)MP_P * N3 * 4, stream);
  k_scatter<<<dim3(EP), 256, 0, stream>>>(h3, agg, p_ei, p_ei + EP, p_ew, deg_p, flag_p, N3);
  k_gather<<<dim3(NB), 256, 0, stream>>>(agg, h3, deg_p, p_index, b_pgo, fc1_in + 1536, N3, N3, KF);

  // ---- encoder: [8192,1344] @ [1344,512] -> BN -> leaky; f32 feature + bf16 into fc1_in ----
  gemm_k<1><<<dim3(NE / 128, NB / 128), 256, 0, stream>>>(
      enc_in, encWt, KEP, fc1_in, KF, feat_out, NE,
      enc_b, enc_g, enc_be, enc_mu, enc_va);

  // ---- fc1: [8192,2560] @ [2560,512] -> leaky -> BN -> f32 ----
  gemm_k<2><<<dim3(NF / 128, NB / 128), 256, 0, stream>>>(
      fc1_in, fc1Wt, KF, nullptr, 0, h_fc1, NF,
      fc1_b, fc_g, fc_be, fc_mu, fc_va);

  // ---- fc2 + relu ----
  k_fc2<<<dim3(NB / 4), 256, 0, stream>>>(h_fc1, fc2_W, fc2_b, y_out);
}

// Round 2
// 1460.143 us; speedup vs baseline: 5.0527x; 5.0527x over previous
//
#include <hip/hip_runtime.h>

typedef unsigned short u16;
typedef __attribute__((ext_vector_type(4))) float f32x4;
typedef __attribute__((ext_vector_type(8))) short s16x8;

// ---------- small helpers ----------
__device__ __forceinline__ u16 f2bf(float f) {
  union { float f; unsigned u; } x; x.f = f;
  unsigned r = x.u + 0x7FFFu + ((x.u >> 16) & 1u);   // RNE
  return (u16)(r >> 16);
}
__device__ __forceinline__ float bf2f(u16 h) {
  union { unsigned u; float f; } x; x.u = ((unsigned)h) << 16;
  return x.f;
}
__device__ __forceinline__ void gload16(const void* g, void* l) {
  __builtin_amdgcn_global_load_lds((__attribute__((address_space(1))) void*)g,
                                   (__attribute__((address_space(3))) void*)l,
                                   16, 0, 0);
}
__device__ __forceinline__ float leaky(float v) { return v >= 0.f ? v : 0.01f * v; }

// ---------- elementwise / prep kernels ----------
__global__ void k_fill(float* __restrict__ p, int n, float v) {
  int i = blockIdx.x * 256 + threadIdx.x;
  if (i < n) p[i] = v;
}
__global__ void k_deg(const int* __restrict__ dst, const float* __restrict__ w,
                      float* __restrict__ deg, int E) {
  int e = blockIdx.x * 256 + threadIdx.x;
  if (e < E) unsafeAtomicAdd(&deg[dst[e]], w[e]);
}
__global__ void k_rsqrt(float* __restrict__ p, int n) {
  int i = blockIdx.x * 256 + threadIdx.x;
  if (i < n) p[i] = rsqrtf(p[i]);   // deg >= 2.0 always (self-loop weight)
}
// x [M,K] f32 -> xb [M,Kpad] bf16 (zero pad K..Kpad). grid: (ceil(Kpad/256), M)
__global__ void k_convert(const float* __restrict__ x, u16* __restrict__ xb,
                          int K, int Kpad) {
  int k = blockIdx.x * 256 + threadIdx.x;
  int m = blockIdx.y;
  if (k >= Kpad) return;
  xb[(size_t)m * Kpad + k] = (k < K) ? f2bf(x[(size_t)m * K + k]) : (u16)0;
}
// W [K,N] f32 -> Wt [Npad,Kpad] bf16 transposed, zero-padded. grid: (Kpad/32, Npad/32)
__global__ void k_wt(const float* __restrict__ W, u16* __restrict__ Wt,
                     int K, int N, int Kpad) {
  __shared__ float t[32][33];
  int tx = threadIdx.x & 31, ty = threadIdx.x >> 5;   // 256 thr: ty 0..7
  int k0 = blockIdx.x * 32, n0 = blockIdx.y * 32;
  #pragma unroll
  for (int r = 0; r < 4; ++r) {
    int k = k0 + ty + r * 8;
    t[ty + r * 8][tx] = (k < K && (n0 + tx) < N) ? W[(size_t)k * N + n0 + tx] : 0.f;
  }
  __syncthreads();
  #pragma unroll
  for (int r = 0; r < 4; ++r) {
    int n = n0 + ty + r * 8;
    Wt[(size_t)n * Kpad + k0 + tx] = f2bf(t[tx][ty + r * 8]);
  }
}
// p_embeddings -> enc_in cols [300,1344). grid: (5, 8192)
__global__ void k_pemb(const float* __restrict__ pe, u16* __restrict__ enc_in) {
  int j = blockIdx.x * 256 + threadIdx.x;
  int b = blockIdx.y;
  if (j >= 1044) return;
  enc_in[(size_t)b * 1344 + 300 + j] =
      (j < 1024) ? f2bf(pe[(size_t)b * 1024 + j]) : (u16)0;
}

// ---------- CSR build ----------
__global__ void k_hist(const int* __restrict__ dst, int* __restrict__ cnt, int E) {
  int e = blockIdx.x * 256 + threadIdx.x;
  if (e < E) atomicAdd(&cnt[dst[e]], 1);
}
// single-block exclusive scan: cnt[N] -> rp[N+1], cur[N]=rp[N]
__global__ void k_scan(const int* __restrict__ cnt, int* __restrict__ rp,
                       int* __restrict__ cur, int N) {
  __shared__ int part[256];
  int t = threadIdx.x;
  int per = (N + 255) / 256;
  int lo = t * per, hi = min(N, lo + per);
  int s = 0;
  for (int j = lo; j < hi; ++j) s += cnt[j];
  int v = s;
  part[t] = s;
  __syncthreads();
  for (int off = 1; off < 256; off <<= 1) {
    int u = (t >= off) ? part[t - off] : 0;
    __syncthreads();
    part[t] += u;
    __syncthreads();
  }
  int base = part[t] - v;    // exclusive prefix of this thread's chunk
  for (int j = lo; j < hi; ++j) {
    rp[j] = base; cur[j] = base; base += cnt[j];
  }
  if (t == 255) rp[N] = base;
}
__global__ void k_csrfill(const int* __restrict__ src, const int* __restrict__ dst,
                          const float* __restrict__ w, const float* __restrict__ dinv,
                          int* __restrict__ cur, int* __restrict__ col,
                          float* __restrict__ nrm, int E) {
  int e = blockIdx.x * 256 + threadIdx.x;
  if (e >= E) return;
  int s = src[e], d = dst[e];
  int p = atomicAdd(&cur[d], 1);
  col[p] = s;
  nrm[p] = dinv[s] * w[e] * dinv[d];
}

// ---------- fused GCN aggregate+gather: one block per sample b ----------
// out[b, 0:Freal) = leaky( sum_e nrm[e]*h[col[e]] + 2*dinv[row]^2*h[row] + bias )
// F = padded row stride of h (mult of 4, <= 1024); 256 threads, one ushort4 each.
__global__ __launch_bounds__(256) void k_aggr(
    const u16* __restrict__ h, const int* __restrict__ rp,
    const int* __restrict__ col, const float* __restrict__ nrm,
    const float* __restrict__ dinv, const int* __restrict__ idx,
    const float* __restrict__ bias, u16* __restrict__ outb,
    int F, int Freal, int ldo)
{
  __shared__ int   s_col[256];
  __shared__ float s_nrm[256];
  const int t = threadIdx.x;
  const int b = blockIdx.x;
  const int row = idx[b];
  const int e0 = rp[row], e1 = rp[row + 1];
  const int i4 = t * 4;
  f32x4 acc = {0.f, 0.f, 0.f, 0.f};

  for (int base = e0; base < e1; base += 256) {
    int n = min(256, e1 - base);
    __syncthreads();
    if (t < n) { s_col[t] = col[base + t]; s_nrm[t] = nrm[base + t]; }
    __syncthreads();
    if (i4 < F) {
      #pragma unroll 4
      for (int j = 0; j < n; ++j) {
        ushort4 hv = *(const ushort4*)(h + (size_t)s_col[j] * F + i4);
        float w = s_nrm[j];
        acc[0] += bf2f(hv.x) * w; acc[1] += bf2f(hv.y) * w;
        acc[2] += bf2f(hv.z) * w; acc[3] += bf2f(hv.w) * w;
      }
    }
  }
  if (i4 < Freal) {
    float sn = dinv[row]; sn = 2.0f * sn * sn;
    ushort4 hv = *(const ushort4*)(h + (size_t)row * F + i4);
    acc[0] += bf2f(hv.x) * sn; acc[1] += bf2f(hv.y) * sn;
    acc[2] += bf2f(hv.z) * sn; acc[3] += bf2f(hv.w) * sn;
    u16* o = outb + (size_t)b * ldo + i4;
    o[0] = f2bf(leaky(acc[0] + bias[i4 + 0]));
    o[1] = f2bf(leaky(acc[1] + bias[i4 + 1]));
    o[2] = f2bf(leaky(acc[2] + bias[i4 + 2]));
    o[3] = f2bf(leaky(acc[3] + bias[i4 + 3]));
  }
}

// ---------- bf16 MFMA GEMM: C[M,N] = A[M,K] @ Bt[N,K]^T ----------
// 128x128 tile, BK=32, 4 waves (2x2), 64x64 per wave, 16x16x32 MFMA.
// EPI 0: store bf16 (h matrices).  EPI 1: +bias, BN, leaky -> f32 + bf16 (encoder).
// EPI 2: +bias, leaky, BN -> f32 (fc1).
template<int EPI>
__global__ __launch_bounds__(256) void gemm_k(
    const u16* __restrict__ A, const u16* __restrict__ Bt, int K,
    u16* __restrict__ Cb, int ldcb, float* __restrict__ Cf, int ldcf,
    const float* __restrict__ bias, const float* __restrict__ gamma,
    const float* __restrict__ beta, const float* __restrict__ mean,
    const float* __restrict__ var)
{
  __shared__ u16 As[2][128 * 32];
  __shared__ u16 Bs[2][128 * 32];
  const int tid = threadIdx.x;
  const int lane = tid & 63, wid = tid >> 6;
  const int wr = wid >> 1, wc = wid & 1;
  const int llo = lane & 15, lhi = lane >> 4;
  const int m0 = blockIdx.y * 128, n0 = blockIdx.x * 128;

  f32x4 acc[4][4] = {};
  const int NT = K >> 5;

  auto stage = [&](int b, int t) {
    const int k0 = t << 5;
    #pragma unroll
    for (int r = 0; r < 2; ++r) {
      const int i  = (r << 8) + (wid << 6) + lane;   // 0..511 segment id
      const int ib = (r << 8) + (wid << 6);          // wave-uniform base
      gload16(A  + (size_t)(m0 + (i >> 2)) * K + (k0 + (i & 3) * 8), &As[b][ib * 8]);
      gload16(Bt + (size_t)(n0 + (i >> 2)) * K + (k0 + (i & 3) * 8), &Bs[b][ib * 8]);
    }
  };

  stage(0, 0);
  int cur = 0;
  for (int t = 0; t < NT; ++t) {
    __syncthreads();                       // buf[cur] staged (vmcnt drained)
    if (t + 1 < NT) stage(cur ^ 1, t + 1); // prefetch next tile
    s16x8 af[4], bfr[4];
    #pragma unroll
    for (int m = 0; m < 4; ++m)
      af[m] = *(const s16x8*)&As[cur][(wr * 64 + m * 16 + llo) * 32 + lhi * 8];
    #pragma unroll
    for (int n = 0; n < 4; ++n)
      bfr[n] = *(const s16x8*)&Bs[cur][(wc * 64 + n * 16 + llo) * 32 + lhi * 8];
    #pragma unroll
    for (int m = 0; m < 4; ++m)
      #pragma unroll
      for (int n = 0; n < 4; ++n)
        acc[m][n] = __builtin_amdgcn_mfma_f32_16x16x32_bf16(af[m], bfr[n], acc[m][n], 0, 0, 0);
    __syncthreads();
    cur ^= 1;
  }

  const int crow = m0 + wr * 64, ccol = n0 + wc * 64;
  #pragma unroll
  for (int n = 0; n < 4; ++n) {
    const int col = ccol + n * 16 + llo;
    float bi = 0.f, g = 0.f, be = 0.f, mu = 0.f, iv = 0.f;
    if constexpr (EPI >= 1) {
      bi = bias[col]; g = gamma[col]; be = beta[col]; mu = mean[col];
      iv = rsqrtf(var[col] + 1e-5f);
    }
    #pragma unroll
    for (int m = 0; m < 4; ++m) {
      #pragma unroll
      for (int j = 0; j < 4; ++j) {
        const int row = crow + m * 16 + lhi * 4 + j;
        float v = acc[m][n][j];
        if constexpr (EPI == 0) {
          Cb[(size_t)row * ldcb + col] = f2bf(v);
        } else if constexpr (EPI == 1) {
          v += bi;
          v = g * (v - mu) * iv + be;     // BN then leaky (encoder)
          v = leaky(v);
          Cf[(size_t)row * ldcf + col] = v;
          Cb[(size_t)row * ldcb + col] = f2bf(v);
        } else {
          v += bi;
          v = leaky(v);                   // leaky then BN (fc)
          v = g * (v - mu) * iv + be;
          Cf[(size_t)row * ldcf + col] = v;
        }
      }
    }
  }
}

// ---------- fc2: y[r] = relu(dot(h[r,:512], w) + b), wave per row ----------
__global__ void k_fc2(const float* __restrict__ h, const float* __restrict__ w,
                      const float* __restrict__ b, float* __restrict__ y) {
  int r = blockIdx.x * 4 + (threadIdx.x >> 6);
  int lane = threadIdx.x & 63;
  const float* hr = h + (size_t)r * 512;
  float s = 0.f;
  #pragma unroll
  for (int j = 0; j < 8; ++j) s += hr[lane + j * 64] * w[lane + j * 64];
  #pragma unroll
  for (int off = 32; off > 0; off >>= 1) s += __shfl_down(s, off);
  if (lane == 0) y[r] = fmaxf(s + b[0], 0.f);
}

// ---------- host ----------
extern "C" void kernel_launch(void* const* d_in, const int* in_sizes, int n_in,
                              void* d_out, int out_size, void* d_ws, size_t ws_size,
                              hipStream_t stream) {
  constexpr int NB  = 8192;
  constexpr int ND  = 10000, NP = 20000;
  constexpr int ED  = 320000, EP = 640000;
  constexpr int K1  = 300, K1P = 320, N1 = 300, N1P = 384;
  constexpr int MD_P = 10112;               // 79*128
  constexpr int K2  = 1024, N2 = 1024;
  constexpr int K3  = 2812, K3P = 2816, N3 = 1024;
  constexpr int MP_P = 20096;               // 4*4096 + 29*128
  constexpr int CH  = 4096;
  constexpr int KE  = 1324, KEP = 1344, NE = 512;
  constexpr int KF  = 2560, NF = 512;

  const int*   d_index = (const int*)d_in[0];
  const int*   p_index = (const int*)d_in[1];
  const float* p_emb   = (const float*)d_in[2];
  const float* d_vecs  = (const float*)d_in[3];
  const float* d_ecfps = (const float*)d_in[4];
  const float* p_gos   = (const float*)d_in[5];
  const int*   d_ei    = (const int*)d_in[6];
  const float* d_ew    = (const float*)d_in[7];
  const int*   p_ei    = (const int*)d_in[8];
  const float* p_ew    = (const float*)d_in[9];
  const float* W_dvec  = (const float*)d_in[10];
  const float* b_dvec  = (const float*)d_in[11];
  const float* W_decfp = (const float*)d_in[12];
  const float* b_decfp = (const float*)d_in[13];
  const float* W_pgo   = (const float*)d_in[14];
  const float* b_pgo   = (const float*)d_in[15];
  const float* enc_W   = (const float*)d_in[16];
  const float* enc_b   = (const float*)d_in[17];
  const float* enc_g   = (const float*)d_in[18];
  const float* enc_be  = (const float*)d_in[19];
  const float* enc_mu  = (const float*)d_in[20];
  const float* enc_va  = (const float*)d_in[21];
  const float* fc1_W   = (const float*)d_in[22];
  const float* fc1_b   = (const float*)d_in[23];
  const float* fc_g    = (const float*)d_in[24];
  const float* fc_be   = (const float*)d_in[25];
  const float* fc_mu   = (const float*)d_in[26];
  const float* fc_va   = (const float*)d_in[27];
  const float* fc2_W   = (const float*)d_in[28];
  const float* fc2_b   = (const float*)d_in[29];

  char* ws = (char*)d_ws;
  size_t off = 0;
  auto alloc = [&](size_t bytes) -> char* {
    char* p = ws + off;
    off += (bytes + 255) & ~(size_t)255;
    return p;
  };
  float* deg_d  = (float*)alloc((size_t)ND * 4);
  float* deg_p  = (float*)alloc((size_t)NP * 4);
  int*   cnt_d  = (int*)  alloc((size_t)ND * 4);
  int*   cnt_p  = (int*)  alloc((size_t)NP * 4);
  int*   rp_d   = (int*)  alloc((size_t)(ND + 1) * 4);
  int*   rp_p   = (int*)  alloc((size_t)(NP + 1) * 4);
  int*   cur_d  = (int*)  alloc((size_t)ND * 4);
  int*   cur_p  = (int*)  alloc((size_t)NP * 4);
  int*   col_d  = (int*)  alloc((size_t)ED * 4);
  float* nrm_d  = (float*)alloc((size_t)ED * 4);
  int*   col_p  = (int*)  alloc((size_t)EP * 4);
  float* nrm_p  = (float*)alloc((size_t)EP * 4);
  u16*   xb1    = (u16*)  alloc((size_t)MD_P * K1P * 2);
  u16*   xb2    = (u16*)  alloc((size_t)MD_P * K2 * 2);
  u16*   xch    = (u16*)  alloc((size_t)CH * K3P * 2);
  u16*   W1t    = (u16*)  alloc((size_t)N1P * K1P * 2);
  u16*   W2t    = (u16*)  alloc((size_t)N2 * K2 * 2);
  u16*   W3t    = (u16*)  alloc((size_t)N3 * K3P * 2);
  u16*   encWt  = (u16*)  alloc((size_t)NE * KEP * 2);
  u16*   fc1Wt  = (u16*)  alloc((size_t)NF * KF * 2);
  u16*   h1     = (u16*)  alloc((size_t)MD_P * N1P * 2);
  u16*   h2     = (u16*)  alloc((size_t)MD_P * N2 * 2);
  u16*   h3     = (u16*)  alloc((size_t)MP_P * N3 * 2);
  u16*   enc_in = (u16*)  alloc((size_t)NB * KEP * 2);
  u16*   fc1_in = (u16*)  alloc((size_t)NB * KF * 2);
  float* h_fc1  = (float*)alloc((size_t)NB * NF * 4);
  if (off > ws_size) return;                              // ws too small: bail loudly

  float* y_out    = (float*)d_out;
  float* feat_out = (float*)d_out + NB;

  // ---- degrees ----
  k_fill<<<dim3((ND + 255) / 256), 256, 0, stream>>>(deg_d, ND, 2.0f);
  k_fill<<<dim3((NP + 255) / 256), 256, 0, stream>>>(deg_p, NP, 2.0f);
  k_deg<<<dim3((ED + 255) / 256), 256, 0, stream>>>(d_ei + ED, d_ew, deg_d, ED);
  k_deg<<<dim3((EP + 255) / 256), 256, 0, stream>>>(p_ei + EP, p_ew, deg_p, EP);
  k_rsqrt<<<dim3((ND + 255) / 256), 256, 0, stream>>>(deg_d, ND);
  k_rsqrt<<<dim3((NP + 255) / 256), 256, 0, stream>>>(deg_p, NP);

  // ---- CSR build (by destination) ----
  hipMemsetAsync(cnt_d, 0, (size_t)ND * 4, stream);
  hipMemsetAsync(cnt_p, 0, (size_t)NP * 4, stream);
  k_hist<<<dim3((ED + 255) / 256), 256, 0, stream>>>(d_ei + ED, cnt_d, ED);
  k_hist<<<dim3((EP + 255) / 256), 256, 0, stream>>>(p_ei + EP, cnt_p, EP);
  k_scan<<<dim3(1), 256, 0, stream>>>(cnt_d, rp_d, cur_d, ND);
  k_scan<<<dim3(1), 256, 0, stream>>>(cnt_p, rp_p, cur_p, NP);
  k_csrfill<<<dim3((ED + 255) / 256), 256, 0, stream>>>(
      d_ei, d_ei + ED, d_ew, deg_d, cur_d, col_d, nrm_d, ED);
  k_csrfill<<<dim3((EP + 255) / 256), 256, 0, stream>>>(
      p_ei, p_ei + EP, p_ew, deg_p, cur_p, col_p, nrm_p, EP);

  // ---- weight transpose-converts (f32 [K,N] -> bf16 [Npad,Kpad]) ----
  k_wt<<<dim3(K1P / 32, N1P / 32), 256, 0, stream>>>(W_dvec, W1t, K1, N1, K1P);
  k_wt<<<dim3(K2 / 32, N2 / 32), 256, 0, stream>>>(W_decfp, W2t, K2, N2, K2);
  k_wt<<<dim3(K3P / 32, N3 / 32), 256, 0, stream>>>(W_pgo, W3t, K3, N3, K3P);
  k_wt<<<dim3(KEP / 32, NE / 32), 256, 0, stream>>>(enc_W, encWt, KE, NE, KEP);
  k_wt<<<dim3(KF / 32, NF / 32), 256, 0, stream>>>(fc1_W, fc1Wt, KF, NF, KF);

  // ---- feature converts ----
  k_convert<<<dim3((K1P + 255) / 256, ND), 256, 0, stream>>>(d_vecs, xb1, K1, K1P);
  k_convert<<<dim3(K2 / 256, ND), 256, 0, stream>>>(d_ecfps, xb2, K2, K2);
  k_pemb<<<dim3(5, NB), 256, 0, stream>>>(p_emb, enc_in);

  // ---- GCN1 (d_vecs, 300->300) ----
  gemm_k<0><<<dim3(N1P / 128, MD_P / 128), 256, 0, stream>>>(
      xb1, W1t, K1P, h1, N1P, nullptr, 0, nullptr, nullptr, nullptr, nullptr, nullptr);
  k_aggr<<<dim3(NB), 256, 0, stream>>>(
      h1, rp_d, col_d, nrm_d, deg_d, d_index, b_dvec, enc_in, N1P, N1, KEP);

  // ---- GCN2 (d_ecfps, 1024->1024) ----
  gemm_k<0><<<dim3(N2 / 128, MD_P / 128), 256, 0, stream>>>(
      xb2, W2t, K2, h2, N2, nullptr, 0, nullptr, nullptr, nullptr, nullptr, nullptr);
  k_aggr<<<dim3(NB), 256, 0, stream>>>(
      h2, rp_d, col_d, nrm_d, deg_d, d_index, b_decfp, fc1_in + 512, N2, N2, KF);

  // ---- GCN3 (p_gos, 2812->1024), chunked conversion to bound ws ----
  for (int c = 0; c < 5; ++c) {
    int r0 = c * CH;
    int rows = (NP - r0 < CH) ? (NP - r0) : CH;
    k_convert<<<dim3((K3P + 255) / 256, rows), 256, 0, stream>>>(
        p_gos + (size_t)r0 * K3, xch, K3, K3P);
    gemm_k<0><<<dim3(N3 / 128, (rows + 127) / 128), 256, 0, stream>>>(
        xch, W3t, K3P, h3 + (size_t)r0 * N3, N3, nullptr, 0,
        nullptr, nullptr, nullptr, nullptr, nullptr);
  }
  k_aggr<<<dim3(NB), 256, 0, stream>>>(
      h3, rp_p, col_p, nrm_p, deg_p, p_index, b_pgo, fc1_in + 1536, N3, N3, KF);

  // ---- encoder: [8192,1344] @ [1344,512] -> BN -> leaky; f32 feature + bf16 into fc1_in ----
  gemm_k<1><<<dim3(NE / 128, NB / 128), 256, 0, stream>>>(
      enc_in, encWt, KEP, fc1_in, KF, feat_out, NE,
      enc_b, enc_g, enc_be, enc_mu, enc_va);

  // ---- fc1: [8192,2560] @ [2560,512] -> leaky -> BN -> f32 ----
  gemm_k<2><<<dim3(NF / 128, NB / 128), 256, 0, stream>>>(
      fc1_in, fc1Wt, KF, nullptr, 0, h_fc1, NF,
      fc1_b, fc_g, fc_be, fc_mu, fc_va);

  // ---- fc2 + relu ----
  k_fc2<<<dim3(NB / 4), 256, 0, stream>>>(h_fc1, fc2_W, fc2_b, y_out);
}